// Round 5
// baseline (235.414 us; speedup 1.0000x reference)
//
#include <hip/hip_runtime.h>
#include <math.h>

// Problem constants (fixed by reference setup_inputs)
constexpr int B = 32, C = 512, N = 1024;   // N = H*W

typedef float f32x4 __attribute__((ext_vector_type(4)));
typedef short s16x8 __attribute__((ext_vector_type(8)));
typedef unsigned short u16x4 __attribute__((ext_vector_type(4)));

// bf16 bit helpers (RNE)
__device__ __forceinline__ unsigned short f32_to_bf16(float v) {
  union { float f; unsigned u; } a; a.f = v;
  unsigned r = (a.u + 0x7FFFu + ((a.u >> 16) & 1u)) >> 16;
  return (unsigned short)r;
}
__device__ __forceinline__ float bf16_to_f32(unsigned short h) {
  union { float f; unsigned u; } a; a.u = ((unsigned)h) << 16;
  return a.f;
}

// async global->LDS, 16B per lane; LDS dest = wave-uniform base + lane*16
__device__ __forceinline__ void glds16(const void* g, void* l) {
  __builtin_amdgcn_global_load_lds((const __attribute__((address_space(1))) void*)g,
                                   (__attribute__((address_space(3))) void*)l, 16, 0, 0);
}

// ---------------------------------------------------------------------------
// Kernel 0: split x (fp32 [B,C,N]) into bf16 hi, lo, and transposed hi [B,N,C].
// ---------------------------------------------------------------------------
__global__ __launch_bounds__(256) void convert_kernel(const float* __restrict__ x,
                                                      unsigned short* __restrict__ xh,
                                                      unsigned short* __restrict__ xl,
                                                      unsigned short* __restrict__ xhT) {
  const int b = blockIdx.z;
  const int cy = blockIdx.y * 64;   // C tile origin
  const int nx = blockIdx.x * 64;   // N tile origin
  const int t = threadIdx.x;
  const int r = t >> 4, c4 = (t & 15) * 4;

  __shared__ unsigned short T[64][68];

#pragma unroll
  for (int rr = 0; rr < 64; rr += 16) {
    const int row = rr + r;
    const size_t gi = ((size_t)b * C + cy + row) * N + nx + c4;
    const float4 v = *(const float4*)&x[gi];
    u16x4 h, l;
    h[0] = f32_to_bf16(v.x); l[0] = f32_to_bf16(v.x - bf16_to_f32(h[0]));
    h[1] = f32_to_bf16(v.y); l[1] = f32_to_bf16(v.y - bf16_to_f32(h[1]));
    h[2] = f32_to_bf16(v.z); l[2] = f32_to_bf16(v.z - bf16_to_f32(h[2]));
    h[3] = f32_to_bf16(v.w); l[3] = f32_to_bf16(v.w - bf16_to_f32(h[3]));
    *(u16x4*)&xh[gi] = h;
    *(u16x4*)&xl[gi] = l;
    T[row][c4 + 0] = h[0]; T[row][c4 + 1] = h[1];
    T[row][c4 + 2] = h[2]; T[row][c4 + 3] = h[3];
  }
  __syncthreads();
#pragma unroll
  for (int rr = 0; rr < 64; rr += 16) {
    const int nrow = rr + r;
    u16x4 o;
    o[0] = T[c4 + 0][nrow]; o[1] = T[c4 + 1][nrow];
    o[2] = T[c4 + 2][nrow]; o[3] = T[c4 + 3][nrow];
    *(u16x4*)&xhT[((size_t)b * N + nx + nrow) * C + cy + c4] = o;
  }
}

// ---------------------------------------------------------------------------
// Kernel 1 (FUSED): rows i0..i0+63 of G = F*F^T (split bf16, 3-MFMA chained),
// then in-block softmax(rowmin - G) -> bf16 A. Full 512-col rows per block, so
// the B-panel (all 512 rows x BK=32) lives in LDS and A-rows are read FROM the
// B-panel (no separate A staging). LDS = exactly 64 KB (hi + lo).
// 512 threads = 8 waves, each 64x64 = 4x4 MFMA tiles; G never hits memory.
// ---------------------------------------------------------------------------
__global__ __launch_bounds__(512, 2) void gram_soft(const unsigned short* __restrict__ xh,
                                                    const unsigned short* __restrict__ xl,
                                                    unsigned short* __restrict__ Abf) {
  const int l = blockIdx.x;
  const int xcd = l & 7, seq = l >> 3;     // 32 blocks per XCD
  const int b = xcd + 8 * (seq >> 3);      // 4 batch-groups per XCD
  const int i0 = (seq & 7) * 64;           // row-tile origin

  const unsigned short* __restrict__ Fh = xh + (size_t)b * C * N;
  const unsigned short* __restrict__ Fl = xl + (size_t)b * C * N;
  unsigned short* __restrict__ Ab = Abf + (size_t)b * C * C;

  __shared__ __align__(16) unsigned short Bh[512 * 32];   // 32 KB
  __shared__ __align__(16) unsigned short Bl[512 * 32];   // 32 KB

  const int t = threadIdx.x, wave = t >> 6, lane = t & 63;
  const int lrow = lane & 15, quad = lane >> 4;
  const int srow = lane >> 2;                     // row within 16-row chunk
  const int sel  = ((lane & 3) ^ (srow & 3)) * 8; // swizzled source granule (64B rows)

  f32x4 acc[4][4] = {};   // [ti: row tiles][tj: col tiles]

  for (int k0 = 0; k0 < N; k0 += 32) {
    __syncthreads();
#pragma unroll
    for (int cc = 0; cc < 4; ++cc) {
      const int chunk = wave * 4 + cc;            // 32 chunks of 16 rows
      const int row = chunk * 16 + srow;
      const size_t g = (size_t)row * N + k0 + sel;
      glds16(Fh + g, &Bh[chunk * 512]);
      glds16(Fl + g, &Bl[chunk * 512]);
    }
    __syncthreads();

    s16x8 ah[4], al[4], bh[4], bl[4];
#pragma unroll
    for (int ti = 0; ti < 4; ++ti) {
      const int r = i0 + ti * 16 + lrow;          // A-rows read from the B-panel
      const int off = r * 32 + (quad ^ (r & 3)) * 8;
      ah[ti] = *(const s16x8*)&Bh[off];
      al[ti] = *(const s16x8*)&Bl[off];
    }
#pragma unroll
    for (int tj = 0; tj < 4; ++tj) {
      const int r = wave * 64 + tj * 16 + lrow;   // wave's 64-col strip
      const int off = r * 32 + (quad ^ (r & 3)) * 8;
      bh[tj] = *(const s16x8*)&Bh[off];
      bl[tj] = *(const s16x8*)&Bl[off];
    }
#pragma unroll
    for (int ti = 0; ti < 4; ++ti)
#pragma unroll
      for (int tj = 0; tj < 4; ++tj) {
        acc[ti][tj] = __builtin_amdgcn_mfma_f32_16x16x32_bf16(ah[ti], bh[tj], acc[ti][tj], 0, 0, 0);
        acc[ti][tj] = __builtin_amdgcn_mfma_f32_16x16x32_bf16(ah[ti], bl[tj], acc[ti][tj], 0, 0, 0);
        acc[ti][tj] = __builtin_amdgcn_mfma_f32_16x16x32_bf16(al[ti], bh[tj], acc[ti][tj], 0, 0, 0);
      }
  }

  // ---- fused softmax epilogue: rows are complete within the block ----
  __syncthreads();                    // all MFMA LDS reads done; reuse LDS
  float* red = (float*)Bh;            // 8 x 64 partials
  float* fin = (float*)Bl;            // 64 finals

  // per-lane min over its 4 cols per row-slot (rows: ti*16 + quad*4 + r)
  float m[16];
#pragma unroll
  for (int ti = 0; ti < 4; ++ti)
#pragma unroll
    for (int r = 0; r < 4; ++r)
      m[ti * 4 + r] = fminf(fminf(acc[ti][0][r], acc[ti][1][r]),
                            fminf(acc[ti][2][r], acc[ti][3][r]));
  // reduce over the 16 lanes (lrow) sharing the same rows
#pragma unroll
  for (int o = 1; o < 16; o <<= 1)
#pragma unroll
    for (int s = 0; s < 16; ++s) m[s] = fminf(m[s], __shfl_xor(m[s], o, 64));
  if (lrow == 0)
#pragma unroll
    for (int ti = 0; ti < 4; ++ti)
#pragma unroll
      for (int r = 0; r < 4; ++r)
        red[wave * 64 + ti * 16 + quad * 4 + r] = m[ti * 4 + r];
  __syncthreads();
  if (t < 64) {
    float v = red[t];
#pragma unroll
    for (int w = 1; w < 8; ++w) v = fminf(v, red[w * 64 + t]);
    fin[t] = v;
  }
  __syncthreads();

  // exponentiate in place, per-lane row sums
  float sm[16];
#pragma unroll
  for (int ti = 0; ti < 4; ++ti)
#pragma unroll
    for (int r = 0; r < 4; ++r) {
      const float mn = fin[ti * 16 + quad * 4 + r];
      float s = 0.f;
#pragma unroll
      for (int tj = 0; tj < 4; ++tj) {
        const float e = __expf(mn - acc[ti][tj][r]);
        acc[ti][tj][r] = e;
        s += e;
      }
      sm[ti * 4 + r] = s;
    }
#pragma unroll
  for (int o = 1; o < 16; o <<= 1)
#pragma unroll
    for (int s = 0; s < 16; ++s) sm[s] += __shfl_xor(sm[s], o, 64);
  if (lrow == 0)
#pragma unroll
    for (int ti = 0; ti < 4; ++ti)
#pragma unroll
      for (int r = 0; r < 4; ++r)
        red[wave * 64 + ti * 16 + quad * 4 + r] = sm[ti * 4 + r];
  __syncthreads();
  if (t < 64) {
    float v = 0.f;
#pragma unroll
    for (int w = 0; w < 8; ++w) v += red[w * 64 + t];
    fin[t] = 1.0f / v;                // fin(min) fully consumed before this sync
  }
  __syncthreads();

  // scale + write bf16 A (16-lane-contiguous u16 segments)
#pragma unroll
  for (int ti = 0; ti < 4; ++ti)
#pragma unroll
    for (int r = 0; r < 4; ++r) {
      const float inv = fin[ti * 16 + quad * 4 + r];
      const int grow = i0 + ti * 16 + quad * 4 + r;
#pragma unroll
      for (int tj = 0; tj < 4; ++tj) {
        const int gcol = wave * 64 + tj * 16 + lrow;
        Ab[(size_t)grow * C + gcol] = f32_to_bf16(acc[ti][tj][r] * inv);
      }
    }
}

// ---------------------------------------------------------------------------
// Kernel 2: E = A*F (bf16 MFMA), out = beta*E + x.
// 128x128 tile, BK=64, 256 threads (4 waves 2x2, each 64x64 = 4x4 MFMA).
// XOR source swizzle. Epilogue: per-wave LDS transpose -> float4 I/O.
// ---------------------------------------------------------------------------
__global__ __launch_bounds__(256, 4) void av_mfma(const unsigned short* __restrict__ Abf,
                                                  const unsigned short* __restrict__ xhT,
                                                  const float* __restrict__ x,
                                                  const float* __restrict__ beta,
                                                  float* __restrict__ out) {
  const int l = blockIdx.x;
  const int xcd = l & 7, seq = l >> 3;
  const int b = xcd + 8 * (seq >> 5);       // 4 batch-groups per XCD
  const int tile = seq & 31;
  const int i0 = (tile >> 3) * 128;         // over C (4)
  const int j0 = (tile & 7) * 128;          // over N (8)

  const unsigned short* __restrict__ Ab = Abf + (size_t)b * C * C;
  const unsigned short* __restrict__ FT = xhT + (size_t)b * N * C;
  const float* __restrict__ xb = x + (size_t)b * C * N;
  float* __restrict__ ob = out + (size_t)b * C * N;

  __shared__ __align__(16) unsigned short SMEM[2 * 128 * 64];   // 32 KB
  unsigned short* As = SMEM;
  unsigned short* Bs = SMEM + 128 * 64;

  const int t = threadIdx.x, wave = t >> 6, lane = t & 63;
  const int wi = wave >> 1, wj = wave & 1;
  const int lrow = lane & 15, quad = lane >> 4;
  const int srow8 = lane >> 3;
  const int sel = ((lane & 7) ^ srow8) * 8;

  f32x4 acc[4][4] = {};

  for (int k0 = 0; k0 < C; k0 += 64) {
    __syncthreads();
#pragma unroll
    for (int cc = 0; cc < 4; ++cc) {
      const int chunk = wave * 4 + cc;
      const int row = chunk * 8 + srow8;
      glds16(Ab + (size_t)(i0 + row) * C + k0 + sel, &As[chunk * 512]);
      glds16(FT + (size_t)(j0 + row) * C + k0 + sel, &Bs[chunk * 512]);
    }
    __syncthreads();

#pragma unroll
    for (int kh = 0; kh < 2; ++kh) {
      s16x8 af[4], bf[4];
#pragma unroll
      for (int ti = 0; ti < 4; ++ti) {
        const int r = wi * 64 + ti * 16 + lrow;
        af[ti] = *(const s16x8*)&As[r * 64 + ((kh * 4 + quad) ^ (r & 7)) * 8];
      }
#pragma unroll
      for (int tj = 0; tj < 4; ++tj) {
        const int r = wj * 64 + tj * 16 + lrow;
        bf[tj] = *(const s16x8*)&Bs[r * 64 + ((kh * 4 + quad) ^ (r & 7)) * 8];
      }
#pragma unroll
      for (int ti = 0; ti < 4; ++ti)
#pragma unroll
        for (int tj = 0; tj < 4; ++tj)
          acc[ti][tj] = __builtin_amdgcn_mfma_f32_16x16x32_bf16(af[ti], bf[tj], acc[ti][tj], 0, 0, 0);
    }
  }

  // Epilogue: per-wave LDS transpose of each 16x64 strip, then float4 I/O.
  __syncthreads();
  float* fs = (float*)SMEM + wave * 1024;   // 4 KB per wave
  const float bv = beta[0];
#pragma unroll
  for (int ti = 0; ti < 4; ++ti) {
#pragma unroll
    for (int tj = 0; tj < 4; ++tj)
#pragma unroll
      for (int r = 0; r < 4; ++r)
        fs[(quad * 4 + r) * 64 + tj * 16 + lrow] = acc[ti][tj][r];
    __syncthreads();
#pragma unroll
    for (int p = 0; p < 4; ++p) {
      const int f = p * 64 + lane;
      const int rr = f >> 4, cc4 = (f & 15) * 4;
      const f32x4 e = *(const f32x4*)&fs[rr * 64 + cc4];
      const int gr = i0 + wi * 64 + ti * 16 + rr;
      const int gc = j0 + wj * 64 + cc4;
      const size_t o = (size_t)gr * N + gc;
      const float4 xv = *(const float4*)&xb[o];
      float4 ov;
      ov.x = fmaf(bv, e[0], xv.x);
      ov.y = fmaf(bv, e[1], xv.y);
      ov.z = fmaf(bv, e[2], xv.z);
      ov.w = fmaf(bv, e[3], xv.w);
      *(float4*)&ob[o] = ov;
    }
    __syncthreads();
  }
}

// ---------------------------------------------------------------------------
extern "C" void kernel_launch(void* const* d_in, const int* in_sizes, int n_in,
                              void* d_out, int out_size, void* d_ws, size_t ws_size,
                              hipStream_t stream) {
  const float* x    = (const float*)d_in[0];
  const float* beta = (const float*)d_in[1];
  float* out = (float*)d_out;

  char* ws = (char*)d_ws;
  unsigned short* xh  = (unsigned short*)ws; ws += (size_t)B * C * N * 2;  // 32 MB
  unsigned short* xl  = (unsigned short*)ws; ws += (size_t)B * C * N * 2;  // 32 MB
  unsigned short* xhT = (unsigned short*)ws; ws += (size_t)B * N * C * 2;  // 32 MB
  unsigned short* Abf = (unsigned short*)ws;                               // 16 MB

  convert_kernel<<<dim3(N / 64, C / 64, B), dim3(256), 0, stream>>>(x, xh, xl, xhT);
  gram_soft     <<<dim3(256),               dim3(512), 0, stream>>>(xh, xl, Abf);
  av_mfma       <<<dim3(1024),              dim3(256), 0, stream>>>(Abf, xhT, x, beta, out);
}

// Round 6
// 210.694 us; speedup vs baseline: 1.1173x; 1.1173x over previous
//
#include <hip/hip_runtime.h>
#include <math.h>

// Problem constants (fixed by reference setup_inputs)
constexpr int B = 32, C = 512, N = 1024;   // N = H*W

typedef float f32x4 __attribute__((ext_vector_type(4)));
typedef _Float16 f16x8 __attribute__((ext_vector_type(8)));
typedef unsigned short u16x4 __attribute__((ext_vector_type(4)));

// fp16 bit helpers
__device__ __forceinline__ unsigned short f32_to_f16u(float v) {
  union { _Float16 h; unsigned short u; } cv; cv.h = (_Float16)v; return cv.u;
}
__device__ __forceinline__ float f16u_to_f32(unsigned short u) {
  union { _Float16 h; unsigned short u; } cv; cv.u = u; return (float)cv.h;
}

// async global->LDS, 16B per lane; LDS dest = wave-uniform base + lane*16
__device__ __forceinline__ void glds16(const void* g, void* l) {
  __builtin_amdgcn_global_load_lds((const __attribute__((address_space(1))) void*)g,
                                   (__attribute__((address_space(3))) void*)l, 16, 0, 0);
}

// ---------------------------------------------------------------------------
// Kernel 0: split x (fp32 [B,C,N]) into fp16 hi (xf), fp16 scaled-lo
// (xlo = fp16((x - hi) * 2048), avoids fp16 subnormals), and transposed hi
// (xfT [B,N,C]). 64x64 tiles, float4 loads, ushort4 stores, LDS transpose.
// ---------------------------------------------------------------------------
__global__ __launch_bounds__(256) void convert_kernel(const float* __restrict__ x,
                                                      unsigned short* __restrict__ xf,
                                                      unsigned short* __restrict__ xlo,
                                                      unsigned short* __restrict__ xfT) {
  const int b = blockIdx.z;
  const int cy = blockIdx.y * 64;   // C tile origin
  const int nx = blockIdx.x * 64;   // N tile origin
  const int t = threadIdx.x;
  const int r = t >> 4, c4 = (t & 15) * 4;

  __shared__ unsigned T[64][65];    // u32 slots: 2-way-max banking both phases

#pragma unroll
  for (int rr = 0; rr < 64; rr += 16) {
    const int row = rr + r;
    const size_t gi = ((size_t)b * C + cy + row) * N + nx + c4;
    const float4 v = *(const float4*)&x[gi];
    u16x4 h, l;
    h[0] = f32_to_f16u(v.x); l[0] = f32_to_f16u((v.x - f16u_to_f32(h[0])) * 2048.0f);
    h[1] = f32_to_f16u(v.y); l[1] = f32_to_f16u((v.y - f16u_to_f32(h[1])) * 2048.0f);
    h[2] = f32_to_f16u(v.z); l[2] = f32_to_f16u((v.z - f16u_to_f32(h[2])) * 2048.0f);
    h[3] = f32_to_f16u(v.w); l[3] = f32_to_f16u((v.w - f16u_to_f32(h[3])) * 2048.0f);
    *(u16x4*)&xf[gi]  = h;
    *(u16x4*)&xlo[gi] = l;
    T[row][c4 + 0] = h[0]; T[row][c4 + 1] = h[1];
    T[row][c4 + 2] = h[2]; T[row][c4 + 3] = h[3];
  }
  __syncthreads();
#pragma unroll
  for (int rr = 0; rr < 64; rr += 16) {
    const int nrow = rr + r;
    u16x4 o;
    o[0] = (unsigned short)T[c4 + 0][nrow]; o[1] = (unsigned short)T[c4 + 1][nrow];
    o[2] = (unsigned short)T[c4 + 2][nrow]; o[3] = (unsigned short)T[c4 + 3][nrow];
    *(u16x4*)&xfT[((size_t)b * N + nx + nrow) * C + cy + c4] = o;
  }
}

// ---------------------------------------------------------------------------
// Kernel 1 (FUSED, double-buffered): rows i0..i0+63 of G = hi*hi^T + 2^-11 *
// (lo_s*hi^T)  (fp16, 2 products; hi*lo^T dropped), then in-block
// softmax(rowmin - G) -> fp16 A.  Hi-panel (512 x BK=32 fp16 = 32 KB) is
// ping-pong double-buffered in 64 KB: glds for iter k+1 issues before compute
// of iter k, so the barrier drain is hidden under ~1300 cyc of MFMA.
// lo A-fragments (block's own 64 rows only) load direct global->VGPR,
// prefetched one iter ahead. XOR swizzle ^((r>>1)&3) -> 2-way (free) banking.
// ---------------------------------------------------------------------------
__global__ __launch_bounds__(512, 2) void gram_soft(const unsigned short* __restrict__ xf,
                                                    const unsigned short* __restrict__ xlo,
                                                    unsigned short* __restrict__ Af) {
  const int l = blockIdx.x;
  const int xcd = l & 7, seq = l >> 3;     // 32 blocks per XCD
  const int b = xcd + 8 * (seq >> 3);      // 4 batch-groups per XCD
  const int i0 = (seq & 7) * 64;           // row-tile origin

  const unsigned short* __restrict__ Fh = xf  + (size_t)b * C * N;
  const unsigned short* __restrict__ Fl = xlo + (size_t)b * C * N;
  unsigned short* __restrict__ Ab = Af + (size_t)b * C * C;

  __shared__ __align__(16) unsigned short P[2][512 * 32];   // 2 x 32 KB

  const int t = threadIdx.x, wave = t >> 6, lane = t & 63;
  const int lrow = lane & 15, quad = lane >> 4;
  const int srow = lane >> 2;                       // row within 16-row chunk
  const int sel  = ((lane & 3) ^ ((lane >> 3) & 3)) * 8;  // swizzled src granule
  const int fsw  = (lrow >> 1) & 3;                 // fragment swizzle term

  f32x4 acc[4][4] = {};   // hi*hi
  f32x4 acl[4][4] = {};   // lo_s*hi (scaled by 2^11)

  // stage hi-panel chunk for k0 into buffer nb
#define STAGE(k0, nb)                                                     \
  {                                                                       \
    _Pragma("unroll")                                                     \
    for (int cc = 0; cc < 4; ++cc) {                                      \
      const int chunk = wave * 4 + cc;                                    \
      const int row = chunk * 16 + srow;                                  \
      glds16(Fh + (size_t)row * N + (k0) + sel, &P[nb][chunk * 512]);     \
    }                                                                     \
  }

  STAGE(0, 0);

  f16x8 alc[4];   // prefetched lo A-frags for current iter
#pragma unroll
  for (int ti = 0; ti < 4; ++ti)
    alc[ti] = *(const f16x8*)&Fl[(size_t)(i0 + ti * 16 + lrow) * N + quad * 8];

  for (int it = 0; it < 32; ++it) {
    const int k0 = it * 32;
    __syncthreads();                       // buf[it&1] staged; prev readers done
    if (it + 1 < 32) STAGE(k0 + 32, (it + 1) & 1);

    f16x8 aln[4];
    if (it + 1 < 32) {
#pragma unroll
      for (int ti = 0; ti < 4; ++ti)
        aln[ti] = *(const f16x8*)&Fl[(size_t)(i0 + ti * 16 + lrow) * N + k0 + 32 + quad * 8];
    }

    const unsigned short* __restrict__ Pc = P[it & 1];
    f16x8 ah[4], bh[4];
#pragma unroll
    for (int ti = 0; ti < 4; ++ti) {
      const int r = i0 + ti * 16 + lrow;
      ah[ti] = *(const f16x8*)&Pc[r * 32 + (quad ^ fsw) * 8];
    }
#pragma unroll
    for (int tj = 0; tj < 4; ++tj) {
      const int r = wave * 64 + tj * 16 + lrow;
      bh[tj] = *(const f16x8*)&Pc[r * 32 + (quad ^ fsw) * 8];
    }
#pragma unroll
    for (int ti = 0; ti < 4; ++ti)
#pragma unroll
      for (int tj = 0; tj < 4; ++tj) {
        acc[ti][tj] = __builtin_amdgcn_mfma_f32_16x16x32_f16(ah[ti],  bh[tj], acc[ti][tj], 0, 0, 0);
        acl[ti][tj] = __builtin_amdgcn_mfma_f32_16x16x32_f16(alc[ti], bh[tj], acl[ti][tj], 0, 0, 0);
      }
    if (it + 1 < 32) {
#pragma unroll
      for (int ti = 0; ti < 4; ++ti) alc[ti] = aln[ti];
    }
  }
#undef STAGE

  // combine: G = acc + 2^-11 * acl
#pragma unroll
  for (int ti = 0; ti < 4; ++ti)
#pragma unroll
    for (int tj = 0; tj < 4; ++tj)
#pragma unroll
      for (int r = 0; r < 4; ++r)
        acc[ti][tj][r] = fmaf(acl[ti][tj][r], 4.8828125e-4f, acc[ti][tj][r]);

  // ---- fused softmax epilogue (rows complete within the block) ----
  __syncthreads();                    // all MFMA LDS reads done; reuse LDS
  float* red = (float*)&P[0][0];      // 8 x 64 partials
  float* fin = (float*)&P[1][0];      // 64 finals

  float m[16];
#pragma unroll
  for (int ti = 0; ti < 4; ++ti)
#pragma unroll
    for (int r = 0; r < 4; ++r)
      m[ti * 4 + r] = fminf(fminf(acc[ti][0][r], acc[ti][1][r]),
                            fminf(acc[ti][2][r], acc[ti][3][r]));
#pragma unroll
  for (int o = 1; o < 16; o <<= 1)
#pragma unroll
    for (int s = 0; s < 16; ++s) m[s] = fminf(m[s], __shfl_xor(m[s], o, 64));
  if (lrow == 0)
#pragma unroll
    for (int ti = 0; ti < 4; ++ti)
#pragma unroll
      for (int r = 0; r < 4; ++r)
        red[wave * 64 + ti * 16 + quad * 4 + r] = m[ti * 4 + r];
  __syncthreads();
  if (t < 64) {
    float v = red[t];
#pragma unroll
    for (int w = 1; w < 8; ++w) v = fminf(v, red[w * 64 + t]);
    fin[t] = v;
  }
  __syncthreads();

  float sm[16];
#pragma unroll
  for (int ti = 0; ti < 4; ++ti)
#pragma unroll
    for (int r = 0; r < 4; ++r) {
      const float mn = fin[ti * 16 + quad * 4 + r];
      float s = 0.f;
#pragma unroll
      for (int tj = 0; tj < 4; ++tj) {
        const float e = __expf(mn - acc[ti][tj][r]);
        acc[ti][tj][r] = e;
        s += e;
      }
      sm[ti * 4 + r] = s;
    }
#pragma unroll
  for (int o = 1; o < 16; o <<= 1)
#pragma unroll
    for (int s = 0; s < 16; ++s) sm[s] += __shfl_xor(sm[s], o, 64);
  if (lrow == 0)
#pragma unroll
    for (int ti = 0; ti < 4; ++ti)
#pragma unroll
      for (int r = 0; r < 4; ++r)
        red[wave * 64 + ti * 16 + quad * 4 + r] = sm[ti * 4 + r];
  __syncthreads();
  if (t < 64) {
    float v = 0.f;
#pragma unroll
    for (int w = 0; w < 8; ++w) v += red[w * 64 + t];
    fin[t] = 1.0f / v;
  }
  __syncthreads();

#pragma unroll
  for (int ti = 0; ti < 4; ++ti)
#pragma unroll
    for (int r = 0; r < 4; ++r) {
      const float inv = fin[ti * 16 + quad * 4 + r];
      const int grow = i0 + ti * 16 + quad * 4 + r;
#pragma unroll
      for (int tj = 0; tj < 4; ++tj) {
        const int gcol = wave * 64 + tj * 16 + lrow;
        Ab[(size_t)grow * C + gcol] = f32_to_f16u(acc[ti][tj][r] * inv);
      }
    }
}

// ---------------------------------------------------------------------------
// Kernel 2: E = A*F (fp16 MFMA), out = beta*E + x.
// 128x128 tile, BK=64, 256 threads (4 waves 2x2, each 64x64 = 4x4 MFMA).
// XOR source swizzle ^(r&7). Epilogue: per-wave LDS transpose -> float4 I/O.
// ---------------------------------------------------------------------------
__global__ __launch_bounds__(256, 4) void av_mfma(const unsigned short* __restrict__ Af,
                                                  const unsigned short* __restrict__ xfT,
                                                  const float* __restrict__ x,
                                                  const float* __restrict__ beta,
                                                  float* __restrict__ out) {
  const int l = blockIdx.x;
  const int xcd = l & 7, seq = l >> 3;
  const int b = xcd + 8 * (seq >> 5);       // 4 batch-groups per XCD
  const int tile = seq & 31;
  const int i0 = (tile >> 3) * 128;         // over C (4)
  const int j0 = (tile & 7) * 128;          // over N (8)

  const unsigned short* __restrict__ Ab = Af  + (size_t)b * C * C;
  const unsigned short* __restrict__ FT = xfT + (size_t)b * N * C;
  const float* __restrict__ xb = x + (size_t)b * C * N;
  float* __restrict__ ob = out + (size_t)b * C * N;

  __shared__ __align__(16) unsigned short SMEM[2 * 128 * 64];   // 32 KB
  unsigned short* As = SMEM;
  unsigned short* Bs = SMEM + 128 * 64;

  const int t = threadIdx.x, wave = t >> 6, lane = t & 63;
  const int wi = wave >> 1, wj = wave & 1;
  const int lrow = lane & 15, quad = lane >> 4;
  const int srow8 = lane >> 3;
  const int sel = ((lane & 7) ^ srow8) * 8;

  f32x4 acc[4][4] = {};

  for (int k0 = 0; k0 < C; k0 += 64) {
    __syncthreads();
#pragma unroll
    for (int cc = 0; cc < 4; ++cc) {
      const int chunk = wave * 4 + cc;
      const int row = chunk * 8 + srow8;
      glds16(Ab + (size_t)(i0 + row) * C + k0 + sel, &As[chunk * 512]);
      glds16(FT + (size_t)(j0 + row) * C + k0 + sel, &Bs[chunk * 512]);
    }
    __syncthreads();

#pragma unroll
    for (int kh = 0; kh < 2; ++kh) {
      f16x8 af[4], bf[4];
#pragma unroll
      for (int ti = 0; ti < 4; ++ti) {
        const int r = wi * 64 + ti * 16 + lrow;
        af[ti] = *(const f16x8*)&As[r * 64 + ((kh * 4 + quad) ^ (r & 7)) * 8];
      }
#pragma unroll
      for (int tj = 0; tj < 4; ++tj) {
        const int r = wj * 64 + tj * 16 + lrow;
        bf[tj] = *(const f16x8*)&Bs[r * 64 + ((kh * 4 + quad) ^ (r & 7)) * 8];
      }
#pragma unroll
      for (int ti = 0; ti < 4; ++ti)
#pragma unroll
        for (int tj = 0; tj < 4; ++tj)
          acc[ti][tj] = __builtin_amdgcn_mfma_f32_16x16x32_f16(af[ti], bf[tj], acc[ti][tj], 0, 0, 0);
    }
  }

  // Epilogue: per-wave LDS transpose of each 16x64 strip, then float4 I/O.
  __syncthreads();
  float* fs = (float*)SMEM + wave * 1024;   // 4 KB per wave
  const float bv = beta[0];
#pragma unroll
  for (int ti = 0; ti < 4; ++ti) {
#pragma unroll
    for (int tj = 0; tj < 4; ++tj)
#pragma unroll
      for (int r = 0; r < 4; ++r)
        fs[(quad * 4 + r) * 64 + tj * 16 + lrow] = acc[ti][tj][r];
    __syncthreads();
#pragma unroll
    for (int p = 0; p < 4; ++p) {
      const int f = p * 64 + lane;
      const int rr = f >> 4, cc4 = (f & 15) * 4;
      const f32x4 e = *(const f32x4*)&fs[rr * 64 + cc4];
      const int gr = i0 + wi * 64 + ti * 16 + rr;
      const int gc = j0 + wj * 64 + cc4;
      const size_t o = (size_t)gr * N + gc;
      const float4 xv = *(const float4*)&xb[o];
      float4 ov;
      ov.x = fmaf(bv, e[0], xv.x);
      ov.y = fmaf(bv, e[1], xv.y);
      ov.z = fmaf(bv, e[2], xv.z);
      ov.w = fmaf(bv, e[3], xv.w);
      *(float4*)&ob[o] = ov;
    }
    __syncthreads();
  }
}

// ---------------------------------------------------------------------------
extern "C" void kernel_launch(void* const* d_in, const int* in_sizes, int n_in,
                              void* d_out, int out_size, void* d_ws, size_t ws_size,
                              hipStream_t stream) {
  const float* x    = (const float*)d_in[0];
  const float* beta = (const float*)d_in[1];
  float* out = (float*)d_out;

  char* ws = (char*)d_ws;
  unsigned short* xf  = (unsigned short*)ws; ws += (size_t)B * C * N * 2;  // 32 MB
  unsigned short* xlo = (unsigned short*)ws; ws += (size_t)B * C * N * 2;  // 32 MB
  unsigned short* xfT = (unsigned short*)ws; ws += (size_t)B * N * C * 2;  // 32 MB
  unsigned short* Af  = (unsigned short*)ws;                               // 16 MB

  convert_kernel<<<dim3(N / 64, C / 64, B), dim3(256), 0, stream>>>(x, xf, xlo, xfT);
  gram_soft     <<<dim3(256),               dim3(512), 0, stream>>>(xf, xlo, Af);
  av_mfma       <<<dim3(1024),              dim3(256), 0, stream>>>(Af, xfT, x, beta, out);
}

// Round 8
// 174.921 us; speedup vs baseline: 1.3458x; 1.2045x over previous
//
#include <hip/hip_runtime.h>
#include <math.h>

// Problem constants (fixed by reference setup_inputs)
constexpr int B = 32, C = 512, N = 1024;   // N = H*W

typedef float f32x4 __attribute__((ext_vector_type(4)));
typedef _Float16 f16x8 __attribute__((ext_vector_type(8)));
typedef unsigned short u16x4 __attribute__((ext_vector_type(4)));

// fp16 bit helpers
__device__ __forceinline__ unsigned short f32_to_f16u(float v) {
  union { _Float16 h; unsigned short u; } cv; cv.h = (_Float16)v; return cv.u;
}
__device__ __forceinline__ float f16u_to_f32(unsigned short u) {
  union { _Float16 h; unsigned short u; } cv; cv.u = u; return (float)cv.h;
}

// async global->LDS, 16B per lane; LDS dest = wave-uniform base + lane*16
__device__ __forceinline__ void glds16(const void* g, void* l) {
  __builtin_amdgcn_global_load_lds((const __attribute__((address_space(1))) void*)g,
                                   (__attribute__((address_space(3))) void*)l, 16, 0, 0);
}

// ---------------------------------------------------------------------------
// Kernel 0: x (fp32 [B,C,N]) -> fp16 xf [B,C,N] and transposed xfT [B,N,C].
// (xlo dropped: single-product Gram.) 64x64 tiles, float4 loads, LDS transpose.
// ---------------------------------------------------------------------------
__global__ __launch_bounds__(256) void convert_kernel(const float* __restrict__ x,
                                                      unsigned short* __restrict__ xf,
                                                      unsigned short* __restrict__ xfT) {
  const int b = blockIdx.z;
  const int cy = blockIdx.y * 64;   // C tile origin
  const int nx = blockIdx.x * 64;   // N tile origin
  const int t = threadIdx.x;
  const int r = t >> 4, c4 = (t & 15) * 4;

  __shared__ unsigned T[64][65];    // u32 slots: 2-way-max banking both phases

#pragma unroll
  for (int rr = 0; rr < 64; rr += 16) {
    const int row = rr + r;
    const size_t gi = ((size_t)b * C + cy + row) * N + nx + c4;
    const float4 v = *(const float4*)&x[gi];
    u16x4 h;
    h[0] = f32_to_f16u(v.x); h[1] = f32_to_f16u(v.y);
    h[2] = f32_to_f16u(v.z); h[3] = f32_to_f16u(v.w);
    *(u16x4*)&xf[gi] = h;
    T[row][c4 + 0] = h[0]; T[row][c4 + 1] = h[1];
    T[row][c4 + 2] = h[2]; T[row][c4 + 3] = h[3];
  }
  __syncthreads();
#pragma unroll
  for (int rr = 0; rr < 64; rr += 16) {
    const int nrow = rr + r;
    u16x4 o;
    o[0] = (unsigned short)T[c4 + 0][nrow]; o[1] = (unsigned short)T[c4 + 1][nrow];
    o[2] = (unsigned short)T[c4 + 2][nrow]; o[3] = (unsigned short)T[c4 + 3][nrow];
    *(u16x4*)&xfT[((size_t)b * N + nx + nrow) * C + cy + c4] = o;
  }
}

// ---------------------------------------------------------------------------
// Kernel 1 (FUSED): rows i0..i0+63 of G = hi*hi^T (single fp16 product), then
// in-block softmax(rowmin - G) -> fp16 A. Full 512-col rows per block; the
// hi-panel (512 x 32 fp16 = 32 KB) is ping-pong double-buffered (64 KB).
// 1024 threads = 16 waves (2 row-halves x 8 col-strips), 4 waves/SIMD for
// ds/MFMA latency overlap. XOR swizzle ^((r>>1)&3): 2-way banking (free).
// ---------------------------------------------------------------------------
__global__ __launch_bounds__(1024, 4) void gram_soft(const unsigned short* __restrict__ xf,
                                                     unsigned short* __restrict__ Af) {
  const int l = blockIdx.x;
  const int xcd = l & 7, seq = l >> 3;     // 32 blocks per XCD
  const int b = xcd + 8 * (seq >> 3);      // 4 batch-groups per XCD
  const int i0 = (seq & 7) * 64;           // row-tile origin

  const unsigned short* __restrict__ Fh = xf + (size_t)b * C * N;
  unsigned short* __restrict__ Ab = Af + (size_t)b * C * C;

  __shared__ __align__(16) unsigned short P[2][512 * 32];   // 2 x 32 KB

  const int t = threadIdx.x, wave = t >> 6, lane = t & 63;
  const int wi = wave >> 3;                // 0..1: 32-row half
  const int wj = wave & 7;                 // 0..7: 64-col strip
  const int lrow = lane & 15, quad = lane >> 4;
  const int srow = lane >> 2;                              // row in 16-row chunk
  const int sel  = ((lane & 3) ^ ((lane >> 3) & 3)) * 8;   // swizzled src granule

  f32x4 acc[2][4] = {};   // [ti: 16-row tiles][tj: 16-col tiles]

#define STAGE(k0, nb)                                                     \
  {                                                                       \
    _Pragma("unroll")                                                     \
    for (int cc = 0; cc < 2; ++cc) {                                      \
      const int chunk = wave * 2 + cc;                                    \
      const int row = chunk * 16 + srow;                                  \
      glds16(Fh + (size_t)row * N + (k0) + sel, &P[nb][chunk * 512]);     \
    }                                                                     \
  }

  STAGE(0, 0);

  for (int it = 0; it < 32; ++it) {
    const int k0 = it * 32;
    __syncthreads();                       // buf[it&1] staged; prev readers done
    if (it + 1 < 32) STAGE(k0 + 32, (it + 1) & 1);

    const unsigned short* __restrict__ Pc = P[it & 1];
    f16x8 ah[2], bh[4];
#pragma unroll
    for (int ti = 0; ti < 2; ++ti) {
      const int r = i0 + wi * 32 + ti * 16 + lrow;
      ah[ti] = *(const f16x8*)&Pc[r * 32 + (quad ^ ((r >> 1) & 3)) * 8];
    }
#pragma unroll
    for (int tj = 0; tj < 4; ++tj) {
      const int r = wj * 64 + tj * 16 + lrow;
      bh[tj] = *(const f16x8*)&Pc[r * 32 + (quad ^ ((r >> 1) & 3)) * 8];
    }
#pragma unroll
    for (int ti = 0; ti < 2; ++ti)
#pragma unroll
      for (int tj = 0; tj < 4; ++tj)
        acc[ti][tj] = __builtin_amdgcn_mfma_f32_16x16x32_f16(ah[ti], bh[tj], acc[ti][tj], 0, 0, 0);
  }
#undef STAGE

  // ---- fused softmax epilogue (rows complete within the block) ----
  __syncthreads();                    // all MFMA LDS reads done; reuse LDS
  float* red = (float*)&P[0][0];      // 16 waves x 32 row-slots
  float* fin = red + 512;             // 64 finals

  // per-lane min over its cols; rows rs = wi*32 + ti*16 + quad*4 + rr
  float m[8];
#pragma unroll
  for (int ti = 0; ti < 2; ++ti)
#pragma unroll
    for (int rr = 0; rr < 4; ++rr)
      m[ti * 4 + rr] = fminf(fminf(acc[ti][0][rr], acc[ti][1][rr]),
                             fminf(acc[ti][2][rr], acc[ti][3][rr]));
#pragma unroll
  for (int o = 1; o < 16; o <<= 1)
#pragma unroll
    for (int s = 0; s < 8; ++s) m[s] = fminf(m[s], __shfl_xor(m[s], o, 64));
  if (lrow == 0)
#pragma unroll
    for (int ti = 0; ti < 2; ++ti)
#pragma unroll
      for (int rr = 0; rr < 4; ++rr)
        red[wave * 32 + ti * 16 + quad * 4 + rr] = m[ti * 4 + rr];
  __syncthreads();
  if (t < 64) {
    const int wig = t >> 5, loc = t & 31;
    float v = red[(wig * 8) * 32 + loc];
#pragma unroll
    for (int j = 1; j < 8; ++j) v = fminf(v, red[(wig * 8 + j) * 32 + loc]);
    fin[t] = v;
  }
  __syncthreads();

  // exponentiate in place, per-lane partial row sums
  float sm[8];
#pragma unroll
  for (int ti = 0; ti < 2; ++ti)
#pragma unroll
    for (int rr = 0; rr < 4; ++rr) {
      const float mn = fin[wi * 32 + ti * 16 + quad * 4 + rr];
      float s = 0.f;
#pragma unroll
      for (int tj = 0; tj < 4; ++tj) {
        const float e = __expf(mn - acc[ti][tj][rr]);
        acc[ti][tj][rr] = e;
        s += e;
      }
      sm[ti * 4 + rr] = s;
    }
#pragma unroll
  for (int o = 1; o < 16; o <<= 1)
#pragma unroll
    for (int s = 0; s < 8; ++s) sm[s] += __shfl_xor(sm[s], o, 64);
  if (lrow == 0)
#pragma unroll
    for (int ti = 0; ti < 2; ++ti)
#pragma unroll
      for (int rr = 0; rr < 4; ++rr)
        red[wave * 32 + ti * 16 + quad * 4 + rr] = sm[ti * 4 + rr];
  __syncthreads();
  if (t < 64) {
    const int wig = t >> 5, loc = t & 31;
    float v = 0.f;
#pragma unroll
    for (int j = 0; j < 8; ++j) v += red[(wig * 8 + j) * 32 + loc];
    fin[t] = 1.0f / v;
  }
  __syncthreads();

  // scale + write fp16 A
#pragma unroll
  for (int ti = 0; ti < 2; ++ti)
#pragma unroll
    for (int rr = 0; rr < 4; ++rr) {
      const float inv = fin[wi * 32 + ti * 16 + quad * 4 + rr];
      const int grow = i0 + wi * 32 + ti * 16 + quad * 4 + rr;
#pragma unroll
      for (int tj = 0; tj < 4; ++tj) {
        const int gcol = wj * 64 + tj * 16 + lrow;
        Ab[(size_t)grow * C + gcol] = f32_to_f16u(acc[ti][tj][rr] * inv);
      }
    }
}

// ---------------------------------------------------------------------------
// Kernel 2: E = A*F (fp16 MFMA), out = beta*E + x  (x residual read as fp16
// xf: |err| <= |x|*4.9e-4, negligible, saves 64 MB fp32 traffic).
// 128x128 tile, BK=64, 256 threads (4 waves 2x2, each 64x64 = 4x4 MFMA).
// XOR source swizzle ^(r&7). Epilogue: LDS transpose -> float4 nontemporal I/O.
// ---------------------------------------------------------------------------
__global__ __launch_bounds__(256, 4) void av_mfma(const unsigned short* __restrict__ Af,
                                                  const unsigned short* __restrict__ xfT,
                                                  const unsigned short* __restrict__ xf,
                                                  const float* __restrict__ beta,
                                                  float* __restrict__ out) {
  const int l = blockIdx.x;
  const int xcd = l & 7, seq = l >> 3;
  const int b = xcd + 8 * (seq >> 5);       // 4 batch-groups per XCD
  const int tile = seq & 31;
  const int i0 = (tile >> 3) * 128;         // over C (4)
  const int j0 = (tile & 7) * 128;          // over N (8)

  const unsigned short* __restrict__ Ab = Af  + (size_t)b * C * C;
  const unsigned short* __restrict__ FT = xfT + (size_t)b * N * C;
  const unsigned short* __restrict__ xb = xf  + (size_t)b * C * N;
  float* __restrict__ ob = out + (size_t)b * C * N;

  __shared__ __align__(16) unsigned short SMEM[2 * 128 * 64];   // 32 KB
  unsigned short* As = SMEM;
  unsigned short* Bs = SMEM + 128 * 64;

  const int t = threadIdx.x, wave = t >> 6, lane = t & 63;
  const int wi = wave >> 1, wj = wave & 1;
  const int lrow = lane & 15, quad = lane >> 4;
  const int srow8 = lane >> 3;
  const int sel = ((lane & 7) ^ srow8) * 8;

  f32x4 acc[4][4] = {};

  for (int k0 = 0; k0 < C; k0 += 64) {
    __syncthreads();
#pragma unroll
    for (int cc = 0; cc < 4; ++cc) {
      const int chunk = wave * 4 + cc;
      const int row = chunk * 8 + srow8;
      glds16(Ab + (size_t)(i0 + row) * C + k0 + sel, &As[chunk * 512]);
      glds16(FT + (size_t)(j0 + row) * C + k0 + sel, &Bs[chunk * 512]);
    }
    __syncthreads();

#pragma unroll
    for (int kh = 0; kh < 2; ++kh) {
      f16x8 af[4], bf[4];
#pragma unroll
      for (int ti = 0; ti < 4; ++ti) {
        const int r = wi * 64 + ti * 16 + lrow;
        af[ti] = *(const f16x8*)&As[r * 64 + ((kh * 4 + quad) ^ (r & 7)) * 8];
      }
#pragma unroll
      for (int tj = 0; tj < 4; ++tj) {
        const int r = wj * 64 + tj * 16 + lrow;
        bf[tj] = *(const f16x8*)&Bs[r * 64 + ((kh * 4 + quad) ^ (r & 7)) * 8];
      }
#pragma unroll
      for (int ti = 0; ti < 4; ++ti)
#pragma unroll
        for (int tj = 0; tj < 4; ++tj)
          acc[ti][tj] = __builtin_amdgcn_mfma_f32_16x16x32_f16(af[ti], bf[tj], acc[ti][tj], 0, 0, 0);
    }
  }

  // Epilogue: per-wave LDS transpose of each 16x64 strip, then vector I/O.
  __syncthreads();
  float* fs = (float*)SMEM + wave * 1024;   // 4 KB per wave
  const float bv = beta[0];
#pragma unroll
  for (int ti = 0; ti < 4; ++ti) {
#pragma unroll
    for (int tj = 0; tj < 4; ++tj)
#pragma unroll
      for (int r = 0; r < 4; ++r)
        fs[(quad * 4 + r) * 64 + tj * 16 + lrow] = acc[ti][tj][r];
    __syncthreads();
#pragma unroll
    for (int p = 0; p < 4; ++p) {
      const int f = p * 64 + lane;
      const int rr = f >> 4, cc4 = (f & 15) * 4;
      const f32x4 e = *(const f32x4*)&fs[rr * 64 + cc4];
      const int gr = i0 + wi * 64 + ti * 16 + rr;
      const int gc = j0 + wj * 64 + cc4;
      const size_t o = (size_t)gr * N + gc;
      const u16x4 xv = *(const u16x4*)&xb[o];
      f32x4 ov;
      ov[0] = fmaf(bv, e[0], f16u_to_f32(xv[0]));
      ov[1] = fmaf(bv, e[1], f16u_to_f32(xv[1]));
      ov[2] = fmaf(bv, e[2], f16u_to_f32(xv[2]));
      ov[3] = fmaf(bv, e[3], f16u_to_f32(xv[3]));
      __builtin_nontemporal_store(ov, (f32x4*)&ob[o]);
    }
    __syncthreads();
  }
}

// ---------------------------------------------------------------------------
extern "C" void kernel_launch(void* const* d_in, const int* in_sizes, int n_in,
                              void* d_out, int out_size, void* d_ws, size_t ws_size,
                              hipStream_t stream) {
  const float* x    = (const float*)d_in[0];
  const float* beta = (const float*)d_in[1];
  float* out = (float*)d_out;

  char* ws = (char*)d_ws;
  unsigned short* xf  = (unsigned short*)ws; ws += (size_t)B * C * N * 2;  // 32 MB
  unsigned short* xfT = (unsigned short*)ws; ws += (size_t)B * N * C * 2;  // 32 MB
  unsigned short* Af  = (unsigned short*)ws;                               // 16 MB

  convert_kernel<<<dim3(N / 64, C / 64, B), dim3(256),  0, stream>>>(x, xf, xfT);
  gram_soft     <<<dim3(256),               dim3(1024), 0, stream>>>(xf, Af);
  av_mfma       <<<dim3(1024),              dim3(256),  0, stream>>>(Af, xfT, xf, beta, out);
}